// Round 7
// baseline (81.803 us; speedup 1.0000x reference)
//
#include <hip/hip_runtime.h>

#define HH 32
#define WW 32
#define NPOS 512
#define TILE 8
#define NTHR 512
#define HSTR 36            // float stride per hi-row: 36 % 32 == 4 -> breaks bank collapse
#define PSTR 580           // float stride per position: 16*36+4; 580 % 32 == 4; 580*4 % 16 == 0
#define NPA 30             // halo mid positions: 3 rows x 10 cols
#define NPB 8              // output positions
#define RSTR 132           // redB float stride per posB: 16*8+4 -> conflict-free final reduce

__device__ __forceinline__ void make_v(const float c[9], float* v) {
    // v[lo] over window elems m=4..8 (MSB-first)
    float a2[2], a4[4], a8[8], a16[16];
    a2[0] = 1.0f - c[4]; a2[1] = c[4];
    #pragma unroll
    for (int i = 0; i < 2; ++i)  { a4[2*i]  = a2[i]  * (1.0f - c[5]); a4[2*i+1]  = a2[i]  * c[5]; }
    #pragma unroll
    for (int i = 0; i < 4; ++i)  { a8[2*i]  = a4[i]  * (1.0f - c[6]); a8[2*i+1]  = a4[i]  * c[6]; }
    #pragma unroll
    for (int i = 0; i < 8; ++i)  { a16[2*i] = a8[i]  * (1.0f - c[7]); a16[2*i+1] = a8[i]  * c[7]; }
    #pragma unroll
    for (int i = 0; i < 16; ++i) { v[2*i]   = a16[i] * (1.0f - c[8]); v[2*i+1]   = a16[i] * c[8]; }
}

// Two fused layers over an 8-wide row tile, 8 batches per block.
__global__ __launch_bounds__(NTHR, 2) void asic_pair(
    const float* __restrict__ src,   // (16,32,32) state before layer A
    const float* __restrict__ tgA,   // (512,32,32) gates, inner layer
    const float* __restrict__ tgB,   // (512,32,32) gates, outer layer
    float* __restrict__ dst)         // (16,32,32) state after layer B
{
    __shared__ float lutA[NPA * PSTR];   // 69.6 KB
    __shared__ float lutB[NPB * PSTR];   // 18.6 KB
    __shared__ float mid[NPA * 8];       // 0.96 KB  (pos-major, 8 local batches)
    __shared__ float redB[NPB * RSTR];   // 4.2 KB

    const int t     = threadIdx.x;        // 0..511
    const int sp    = blockIdx.x & 127;
    const int bhalf = blockIdx.x >> 7;    // blocks i, i+128 land on same XCD -> share gate L2 lines
    const int hw0   = sp * TILE;
    const int h     = hw0 >> 5;
    const int w0    = hw0 & 31;           // 0,8,16,24

    // ================= stage sigmoid LUTs =================
    // lutA: 30 pos x 512 p  (lanes sweep ~2 planes' positions -> decent coalescing)
    #pragma unroll 5
    for (int k = 0; k < NPA; ++k) {
        unsigned f = t + NTHR * k;        // 0..15359
        unsigned p = f / 30u;
        unsigned pos = f - 30u * p;
        unsigned i  = pos / 10u;
        unsigned jj = pos - 10u * i;
        int rm = (h + (int)i) & 31;
        int cm = (w0 - 1 + (int)jj + 32) & 31;
        float g = tgA[p * (HH * WW) + rm * 32 + cm];
        lutA[pos * PSTR + (p >> 5) * HSTR + (p & 31)] = 1.0f / (1.0f + __expf(-g));
    }
    // lutB: 8 pos x 512 p
    #pragma unroll 4
    for (int k = 0; k < NPB; ++k) {
        unsigned f = t + NTHR * k;        // 0..4095
        unsigned p  = f >> 3;
        unsigned pb = f & 7;
        float g = tgB[p * (HH * WW) + h * 32 + (w0 + (int)pb)];
        lutB[pb * PSTR + (p >> 5) * HSTR + (p & 31)] = 1.0f / (1.0f + __expf(-g));
    }

    // ================= phase A setup (before sync: overlap gather with staging) =================
    const int hs  = t & 7;                // hi = 2*hs, 2*hs+1
    const int bg  = (t >> 3) & 1;        // batch group of 4
    const int pos = t >> 4;              // 0..31, active < 30
    const unsigned ip  = (unsigned)pos / 10u;
    const unsigned jjp = (unsigned)pos - 10u * ip;
    const int rmA  = h + (int)ip;
    const int cmbA = w0 - 1 + (int)jjp;   // [-1, 33]
    const int b0   = bhalf * 8 + bg * 4;

    const int m0 = (hs >> 2) & 1, m1 = (hs >> 1) & 1, m2 = hs & 1;

    float vA[4][32], ubase[4], c3v[4];
    #pragma unroll
    for (int bb = 0; bb < 4; ++bb) {
        const float* sb = src + (size_t)(b0 + bb) * (HH * WW);
        float c[9];
        #pragma unroll
        for (int ii = 0; ii < 3; ++ii) {
            int row = ((rmA + ii) & 31) * 32;
            #pragma unroll
            for (int ji = 0; ji < 3; ++ji) {
                c[3 * ii + ji] = sb[row + ((cmbA + ji - 1 + 32) & 31)];
            }
        }
        make_v(c, vA[bb]);
        float f0 = m0 ? c[0] : 1.0f - c[0];
        float f1 = m1 ? c[1] : 1.0f - c[1];
        float f2 = m2 ? c[2] : 1.0f - c[2];
        ubase[bb] = f0 * f1 * f2;
        c3v[bb]   = c[3];
    }

    __syncthreads();   // LUTs ready

    // ================= phase A dot: 2 hi x 8 float4 reads, 4 batches per read =================
    float acc[4] = {0.f, 0.f, 0.f, 0.f};
    {
        const float* baseA = lutA + pos * PSTR + (2 * hs) * HSTR;
        #pragma unroll
        for (int hp = 0; hp < 2; ++hp) {
            const float4* L4 = (const float4*)(baseA + hp * HSTR);
            float ps[4] = {0.f, 0.f, 0.f, 0.f};
            #pragma unroll
            for (int l4 = 0; l4 < 8; ++l4) {
                float4 L = L4[l4];
                #pragma unroll
                for (int bb = 0; bb < 4; ++bb) {
                    ps[bb] = fmaf(L.x, vA[bb][4*l4+0], ps[bb]);
                    ps[bb] = fmaf(L.y, vA[bb][4*l4+1], ps[bb]);
                    ps[bb] = fmaf(L.z, vA[bb][4*l4+2], ps[bb]);
                    ps[bb] = fmaf(L.w, vA[bb][4*l4+3], ps[bb]);
                }
            }
            #pragma unroll
            for (int bb = 0; bb < 4; ++bb) {
                float u = ubase[bb] * (hp ? c3v[bb] : (1.0f - c3v[bb]));
                acc[bb] = fmaf(u, ps[bb], acc[bb]);
            }
        }
    }
    // butterfly over hs lanes (t bits 0..2): stays within (bg,pos) group
    #pragma unroll
    for (int mask = 1; mask <= 4; mask <<= 1) {
        #pragma unroll
        for (int bb = 0; bb < 4; ++bb) acc[bb] += __shfl_xor(acc[bb], mask, 64);
    }
    if (hs == 0 && pos < NPA) {
        float4 m4;
        m4.x = fminf(fmaxf(acc[0], 0.0f), 1.0f);
        m4.y = fminf(fmaxf(acc[1], 0.0f), 1.0f);
        m4.z = fminf(fmaxf(acc[2], 0.0f), 1.0f);
        m4.w = fminf(fmaxf(acc[3], 0.0f), 1.0f);
        *(float4*)(mid + pos * 8 + bg * 4) = m4;   // [pos][b_local]
    }
    __syncthreads();   // mid ready

    // ================= phase B: posB x 2-batch x single-hi =================
    {
        const int posB = t >> 6;          // 0..7 (constant per wave)
        const int bp   = (t >> 4) & 3;    // local batches 2bp, 2bp+1
        const int hi   = t & 15;

        float c0[9], c1[9];
        #pragma unroll
        for (int wi = 0; wi < 3; ++wi) {
            #pragma unroll
            for (int wj = 0; wj < 3; ++wj) {
                float2 m = *(const float2*)(mid + (wi * 10 + posB + wj) * 8 + bp * 2);
                c0[3 * wi + wj] = m.x;
                c1[3 * wi + wj] = m.y;
            }
        }
        float v0[32], v1[32];
        make_v(c0, v0);
        make_v(c1, v1);

        const int hm0 = (hi >> 3) & 1, hm1 = (hi >> 2) & 1, hm2 = (hi >> 1) & 1, hm3 = hi & 1;
        float u0 = (hm0 ? c0[0] : 1.0f - c0[0]) * (hm1 ? c0[1] : 1.0f - c0[1])
                 * (hm2 ? c0[2] : 1.0f - c0[2]) * (hm3 ? c0[3] : 1.0f - c0[3]);
        float u1 = (hm0 ? c1[0] : 1.0f - c1[0]) * (hm1 ? c1[1] : 1.0f - c1[1])
                 * (hm2 ? c1[2] : 1.0f - c1[2]) * (hm3 ? c1[3] : 1.0f - c1[3]);

        const float4* L4 = (const float4*)(lutB + posB * PSTR + hi * HSTR);
        float p0a = 0.f, p0b = 0.f, p1a = 0.f, p1b = 0.f;
        #pragma unroll
        for (int l4 = 0; l4 < 8; ++l4) {
            float4 L = L4[l4];
            p0a = fmaf(L.x, v0[4*l4+0], p0a); p0a = fmaf(L.y, v0[4*l4+1], p0a);
            p0b = fmaf(L.z, v0[4*l4+2], p0b); p0b = fmaf(L.w, v0[4*l4+3], p0b);
            p1a = fmaf(L.x, v1[4*l4+0], p1a); p1a = fmaf(L.y, v1[4*l4+1], p1a);
            p1b = fmaf(L.z, v1[4*l4+2], p1b); p1b = fmaf(L.w, v1[4*l4+3], p1b);
        }
        float2 r;
        r.x = u0 * (p0a + p0b);
        r.y = u1 * (p1a + p1b);
        *(float2*)(redB + posB * RSTR + hi * 8 + bp * 2) = r;
    }
    __syncthreads();

    // ================= final reduce + store =================
    if (t < 64) {
        int posB = t >> 3;
        int bl   = t & 7;
        const float* rb = redB + posB * RSTR + bl;
        float s = 0.0f;
        #pragma unroll
        for (int hi = 0; hi < 16; ++hi) s += rb[hi * 8];
        s = fminf(fmaxf(s, 0.0f), 1.0f);
        dst[(size_t)(bhalf * 8 + bl) * (HH * WW) + h * 32 + (w0 + posB)] = s;
    }
}

extern "C" void kernel_launch(void* const* d_in, const int* in_sizes, int n_in,
                              void* d_out, int out_size, void* d_ws, size_t ws_size,
                              hipStream_t stream) {
    const float* x  = (const float*)d_in[0];   // (16,32,32)
    const float* tg = (const float*)d_in[1];   // (4,512,32,32)
    float* out = (float*)d_out;
    float* ws  = (float*)d_ws;                 // 64 KB used

    const int grid = 256;                      // 128 spatial tiles x 2 batch halves
    const size_t L = (size_t)NPOS * HH * WW;

    // layers 0+1 fused, then 2+3 fused; kernel boundary = coherence point
    asic_pair<<<grid, NTHR, 0, stream>>>(x,  tg + 0 * L, tg + 1 * L, ws);
    asic_pair<<<grid, NTHR, 0, stream>>>(ws, tg + 2 * L, tg + 3 * L, out);
}

// Round 8
// 81.205 us; speedup vs baseline: 1.0074x; 1.0074x over previous
//
#include <hip/hip_runtime.h>

#define HH 32
#define WW 32
#define NPOS 512
#define TILE 8
#define NTHR 512
#define HSTR 36            // float stride per hi-row: 36 % 32 == 4 -> breaks bank collapse
#define PSTR 580           // float stride per position: 16*36+4; 580 % 32 == 4; 580*4 % 16 == 0
#define NPA 30             // halo mid positions: 3 rows x 10 cols
#define NPB 8              // output positions
#define RSTR 132           // redB float stride per posB: 16*8+4 -> conflict-free final reduce

__device__ __forceinline__ void make_v(const float c[9], float* v) {
    // v[lo] over window elems m=4..8 (MSB-first)
    float a2[2], a4[4], a8[8], a16[16];
    a2[0] = 1.0f - c[4]; a2[1] = c[4];
    #pragma unroll
    for (int i = 0; i < 2; ++i)  { a4[2*i]  = a2[i]  * (1.0f - c[5]); a4[2*i+1]  = a2[i]  * c[5]; }
    #pragma unroll
    for (int i = 0; i < 4; ++i)  { a8[2*i]  = a4[i]  * (1.0f - c[6]); a8[2*i+1]  = a4[i]  * c[6]; }
    #pragma unroll
    for (int i = 0; i < 8; ++i)  { a16[2*i] = a8[i]  * (1.0f - c[7]); a16[2*i+1] = a8[i]  * c[7]; }
    #pragma unroll
    for (int i = 0; i < 16; ++i) { v[2*i]   = a16[i] * (1.0f - c[8]); v[2*i+1]   = a16[i] * c[8]; }
}

// Two fused layers over an 8-wide row tile, 8 batches per block.
// Register-pressure-fixed rework of r7: phase A = 2 batches/thread (not 4).
__global__ __launch_bounds__(NTHR) void asic_pair(
    const float* __restrict__ src,   // (16,32,32) state before layer A
    const float* __restrict__ tgA,   // (512,32,32) gates, inner layer
    const float* __restrict__ tgB,   // (512,32,32) gates, outer layer
    float* __restrict__ dst)         // (16,32,32) state after layer B
{
    __shared__ float lutA[NPA * PSTR];   // 69.6 KB
    __shared__ float lutB[NPB * PSTR];   // 18.6 KB
    __shared__ float mid[NPA * 8];       // 0.96 KB  (pos-major, 8 local batches)
    __shared__ float redB[NPB * RSTR];   // 4.2 KB

    const int t     = threadIdx.x;        // 0..511
    const int sp    = blockIdx.x & 127;
    const int bhalf = blockIdx.x >> 7;    // blocks i, i+128 share gate L2 lines
    const int hw0   = sp * TILE;
    const int h     = hw0 >> 5;
    const int w0    = hw0 & 31;           // 0,8,16,24

    // ================= stage sigmoid LUTs =================
    #pragma unroll 5
    for (int k = 0; k < NPA; ++k) {
        unsigned f = t + NTHR * k;        // 0..15359
        unsigned p = f / 30u;
        unsigned pos = f - 30u * p;
        unsigned i  = pos / 10u;
        unsigned jj = pos - 10u * i;
        int rm = (h + (int)i) & 31;
        int cm = (w0 - 1 + (int)jj + 32) & 31;
        float g = tgA[p * (HH * WW) + rm * 32 + cm];
        lutA[pos * PSTR + (p >> 5) * HSTR + (p & 31)] = 1.0f / (1.0f + __expf(-g));
    }
    #pragma unroll 4
    for (int k = 0; k < NPB; ++k) {
        unsigned f = t + NTHR * k;        // 0..4095
        unsigned p  = f >> 3;
        unsigned pb = f & 7;
        float g = tgB[p * (HH * WW) + h * 32 + (w0 + (int)pb)];
        lutB[pb * PSTR + (p >> 5) * HSTR + (p & 31)] = 1.0f / (1.0f + __expf(-g));
    }

    // ================= phase A setup (gathers before sync: overlap with staging) =================
    // t = pos*16 + bg*4 + hs : hs -> hi bits m0,m1 ; thread covers hi = 4*hs .. 4*hs+3
    const int hs  = t & 3;
    const int bg  = (t >> 2) & 3;         // 2 batches per group
    const int pos = t >> 4;               // 0..31, active < 30
    const unsigned ip  = (unsigned)pos / 10u;
    const unsigned jjp = (unsigned)pos - 10u * ip;
    const int rmA  = h + (int)ip;
    const int cmbA = w0 - 1 + (int)jjp;   // [-1, 33]
    const int b0   = bhalf * 8 + bg * 2;

    const int m0 = (hs >> 1) & 1, m1 = hs & 1;

    float vA[2][32], ubase[2], c2v[2], c3v[2];
    #pragma unroll
    for (int bb = 0; bb < 2; ++bb) {
        const float* sb = src + (size_t)(b0 + bb) * (HH * WW);
        float c[9];
        #pragma unroll
        for (int ii = 0; ii < 3; ++ii) {
            int row = ((rmA + ii) & 31) * 32;
            #pragma unroll
            for (int ji = 0; ji < 3; ++ji) {
                c[3 * ii + ji] = sb[row + ((cmbA + ji - 1 + 32) & 31)];
            }
        }
        make_v(c, vA[bb]);
        ubase[bb] = (m0 ? c[0] : 1.0f - c[0]) * (m1 ? c[1] : 1.0f - c[1]);
        c2v[bb]   = c[2];
        c3v[bb]   = c[3];
    }

    __syncthreads();   // LUTs ready

    // ================= phase A dot: 4 hi x 8 float4 reads, 2 batches per read =================
    float acc0 = 0.f, acc1 = 0.f;
    {
        const float* baseA = lutA + pos * PSTR + (4 * hs) * HSTR;
        #pragma unroll
        for (int hp = 0; hp < 4; ++hp) {       // hi = 4*hs + hp ; hp -> bits m2,m3
            const float4* L4 = (const float4*)(baseA + hp * HSTR);
            float p0a = 0.f, p0b = 0.f, p1a = 0.f, p1b = 0.f;
            #pragma unroll
            for (int l4 = 0; l4 < 8; ++l4) {
                float4 L = L4[l4];
                p0a = fmaf(L.x, vA[0][4*l4+0], p0a); p0a = fmaf(L.y, vA[0][4*l4+1], p0a);
                p0b = fmaf(L.z, vA[0][4*l4+2], p0b); p0b = fmaf(L.w, vA[0][4*l4+3], p0b);
                p1a = fmaf(L.x, vA[1][4*l4+0], p1a); p1a = fmaf(L.y, vA[1][4*l4+1], p1a);
                p1b = fmaf(L.z, vA[1][4*l4+2], p1b); p1b = fmaf(L.w, vA[1][4*l4+3], p1b);
            }
            float f2_0 = (hp & 2) ? c2v[0] : 1.0f - c2v[0];
            float f3_0 = (hp & 1) ? c3v[0] : 1.0f - c3v[0];
            float f2_1 = (hp & 2) ? c2v[1] : 1.0f - c2v[1];
            float f3_1 = (hp & 1) ? c3v[1] : 1.0f - c3v[1];
            acc0 = fmaf(ubase[0] * f2_0 * f3_0, p0a + p0b, acc0);
            acc1 = fmaf(ubase[1] * f2_1 * f3_1, p1a + p1b, acc1);
        }
    }
    // butterfly over hs lanes (t bits 0..1): stays within (bg,pos) group
    #pragma unroll
    for (int mask = 1; mask <= 2; mask <<= 1) {
        acc0 += __shfl_xor(acc0, mask, 64);
        acc1 += __shfl_xor(acc1, mask, 64);
    }
    if (hs == 0 && pos < NPA) {
        float2 m2v;
        m2v.x = fminf(fmaxf(acc0, 0.0f), 1.0f);
        m2v.y = fminf(fmaxf(acc1, 0.0f), 1.0f);
        *(float2*)(mid + pos * 8 + bg * 2) = m2v;   // [pos][b_local]
    }
    __syncthreads();   // mid ready

    // ================= phase B: posB x 2-batch x single-hi =================
    {
        const int posB = t >> 6;          // 0..7 (constant per wave)
        const int bp   = (t >> 4) & 3;    // local batches 2bp, 2bp+1
        const int hi   = t & 15;

        float c0[9], c1[9];
        #pragma unroll
        for (int wi = 0; wi < 3; ++wi) {
            #pragma unroll
            for (int wj = 0; wj < 3; ++wj) {
                float2 m = *(const float2*)(mid + (wi * 10 + posB + wj) * 8 + bp * 2);
                c0[3 * wi + wj] = m.x;
                c1[3 * wi + wj] = m.y;
            }
        }
        float v0[32], v1[32];
        make_v(c0, v0);
        make_v(c1, v1);

        const int hm0 = (hi >> 3) & 1, hm1 = (hi >> 2) & 1, hm2 = (hi >> 1) & 1, hm3 = hi & 1;
        float u0 = (hm0 ? c0[0] : 1.0f - c0[0]) * (hm1 ? c0[1] : 1.0f - c0[1])
                 * (hm2 ? c0[2] : 1.0f - c0[2]) * (hm3 ? c0[3] : 1.0f - c0[3]);
        float u1 = (hm0 ? c1[0] : 1.0f - c1[0]) * (hm1 ? c1[1] : 1.0f - c1[1])
                 * (hm2 ? c1[2] : 1.0f - c1[2]) * (hm3 ? c1[3] : 1.0f - c1[3]);

        const float4* L4 = (const float4*)(lutB + posB * PSTR + hi * HSTR);
        float p0a = 0.f, p0b = 0.f, p1a = 0.f, p1b = 0.f;
        #pragma unroll
        for (int l4 = 0; l4 < 8; ++l4) {
            float4 L = L4[l4];
            p0a = fmaf(L.x, v0[4*l4+0], p0a); p0a = fmaf(L.y, v0[4*l4+1], p0a);
            p0b = fmaf(L.z, v0[4*l4+2], p0b); p0b = fmaf(L.w, v0[4*l4+3], p0b);
            p1a = fmaf(L.x, v1[4*l4+0], p1a); p1a = fmaf(L.y, v1[4*l4+1], p1a);
            p1b = fmaf(L.z, v1[4*l4+2], p1b); p1b = fmaf(L.w, v1[4*l4+3], p1b);
        }
        float2 r;
        r.x = u0 * (p0a + p0b);
        r.y = u1 * (p1a + p1b);
        *(float2*)(redB + posB * RSTR + hi * 8 + bp * 2) = r;
    }
    __syncthreads();

    // ================= final reduce + store =================
    if (t < 64) {
        int posB = t >> 3;
        int bl   = t & 7;
        const float* rb = redB + posB * RSTR + bl;
        float s = 0.0f;
        #pragma unroll
        for (int hi = 0; hi < 16; ++hi) s += rb[hi * 8];
        s = fminf(fmaxf(s, 0.0f), 1.0f);
        dst[(size_t)(bhalf * 8 + bl) * (HH * WW) + h * 32 + (w0 + posB)] = s;
    }
}

extern "C" void kernel_launch(void* const* d_in, const int* in_sizes, int n_in,
                              void* d_out, int out_size, void* d_ws, size_t ws_size,
                              hipStream_t stream) {
    const float* x  = (const float*)d_in[0];   // (16,32,32)
    const float* tg = (const float*)d_in[1];   // (4,512,32,32)
    float* out = (float*)d_out;
    float* ws  = (float*)d_ws;                 // 64 KB used

    const int grid = 256;                      // 128 spatial tiles x 2 batch halves
    const size_t L = (size_t)NPOS * HH * WW;

    // layers 0+1 fused, then 2+3 fused; kernel boundary = coherence point
    asic_pair<<<grid, NTHR, 0, stream>>>(x,  tg + 0 * L, tg + 1 * L, ws);
    asic_pair<<<grid, NTHR, 0, stream>>>(ws, tg + 2 * L, tg + 3 * L, out);
}